// Round 1
// baseline (949.321 us; speedup 1.0000x reference)
//
#include <hip/hip_runtime.h>
#include <math.h>

// Problem constants
#define TSEQ   1024
#define DMODEL 256
#define NHEAD  8
#define DHEAD  32
#define NBH    64        // B*H
#define NREL   2047      // 2T-1
#define OUT0   2097152   // B*T*D elements (output 0 size)

// workspace offsets (floats); total = 9,436,672 floats = 37.75 MB
#define Q_OFF   0u
#define K_OFF   2097152u
#define V_OFF   4194304u
#define P_OFF   6291456u
#define O_OFF   6815488u
#define PE_OFF  8912640u

// ---------------------------------------------------------------------------
// Sinusoidal relative PE table: pe[r][col], r=0..2046 (pos = r-1023), col=0..255
// even col -> sin, odd col -> cos; computed in double for accuracy.
__global__ __launch_bounds__(256) void pe_kernel(float* __restrict__ pe) {
  int idx = blockIdx.x * 256 + threadIdx.x;   // exactly 2047*256 threads
  int r = idx >> 8;
  int col = idx & 255;
  int m = col >> 1;
  double denom = exp((double)(2 * m) * (-9.210340371976184 / 256.0)); // -ln(1e4)/256
  double ang = (double)(r - 1023) * denom;
  pe[idx] = (col & 1) ? (float)cos(ang) : (float)sin(ang);
}

// ---------------------------------------------------------------------------
// QKV projection: C[bt][c] = sum_k X[bt][k]*W[c][k] + bias[c], c in [0,768)
// grid (128, 12), block 256. BM=BN=64, BK=32, 4x4 micro-tile.
// Epilogue scatters into [B,H,T,DH] layout.
__global__ __launch_bounds__(256) void proj_qkv_kernel(
    const float* __restrict__ X,
    const float* __restrict__ Wq, const float* __restrict__ Wk, const float* __restrict__ Wv,
    const float* __restrict__ bq, const float* __restrict__ bk, const float* __restrict__ bv,
    float* __restrict__ qbuf, float* __restrict__ kbuf, float* __restrict__ vbuf)
{
  __shared__ float Xs[32][68];   // [kk][row], stride 68 floats = 272B (16B aligned)
  __shared__ float Ws[32][68];   // [kk][col]
  const int bm = blockIdx.x;
  const int bn = blockIdx.y;            // 0..11
  const int sel = bn >> 2;              // 0=q, 1=k, 2=v
  const float* W   = sel == 0 ? Wq : (sel == 1 ? Wk : Wv);
  const float* bia = sel == 0 ? bq : (sel == 1 ? bk : bv);
  float* dst       = sel == 0 ? qbuf : (sel == 1 ? kbuf : vbuf);
  const int c0  = (bn & 3) * 64;        // column offset within [0,256)
  const int bt0 = bm * 64;
  const int tid = threadIdx.x;
  const int tx = tid & 15, ty = tid >> 4;
  float acc[4][4] = {};

  for (int k0 = 0; k0 < 256; k0 += 32) {
    __syncthreads();
    int c = tid;
    for (int l = 0; l < 2; ++l, c += 256) {
      int row = c >> 3, kq = (c & 7) * 4;
      float4 x4 = *(const float4*)&X[(size_t)(bt0 + row) * 256 + k0 + kq];
      Xs[kq + 0][row] = x4.x; Xs[kq + 1][row] = x4.y;
      Xs[kq + 2][row] = x4.z; Xs[kq + 3][row] = x4.w;
    }
    c = tid;
    for (int l = 0; l < 2; ++l, c += 256) {
      int row = c >> 3, kq = (c & 7) * 4;
      float4 w4 = *(const float4*)&W[(size_t)(c0 + row) * 256 + k0 + kq];
      Ws[kq + 0][row] = w4.x; Ws[kq + 1][row] = w4.y;
      Ws[kq + 2][row] = w4.z; Ws[kq + 3][row] = w4.w;
    }
    __syncthreads();
#pragma unroll
    for (int kk = 0; kk < 32; ++kk) {
      float4 a4 = *(const float4*)&Xs[kk][ty * 4];
      float4 b4 = *(const float4*)&Ws[kk][tx * 4];
      float av[4] = {a4.x, a4.y, a4.z, a4.w};
      float bv_[4] = {b4.x, b4.y, b4.z, b4.w};
#pragma unroll
      for (int i = 0; i < 4; ++i)
#pragma unroll
        for (int j = 0; j < 4; ++j) acc[i][j] += av[i] * bv_[j];
    }
  }
#pragma unroll
  for (int j = 0; j < 4; ++j) {
    int dcol = c0 + tx * 4 + j;
    float bz = bia[dcol];
    int h = dcol >> 5, dd = dcol & 31;
#pragma unroll
    for (int i = 0; i < 4; ++i) {
      int bt = bt0 + ty * 4 + i;
      int bb = bt >> 10, t = bt & 1023;
      dst[(((size_t)bb * NHEAD + h) * TSEQ + t) * DHEAD + dd] = acc[i][j] + bz;
    }
  }
}

// ---------------------------------------------------------------------------
// P projection: P[r][c] = sum_k pe[r][k]*Wp[c][k]; grid (32,4) rows 2047 (guarded)
// Epilogue stores as [H][NREL][DH].
__global__ __launch_bounds__(256) void pgemm_kernel(
    const float* __restrict__ pe, const float* __restrict__ Wp, float* __restrict__ pbuf)
{
  __shared__ float Xs[32][68];
  __shared__ float Ws[32][68];
  const int bm = blockIdx.x;
  const int bn = blockIdx.y;
  const int c0  = bn * 64;
  const int bt0 = bm * 64;
  const int tid = threadIdx.x;
  const int tx = tid & 15, ty = tid >> 4;
  float acc[4][4] = {};

  for (int k0 = 0; k0 < 256; k0 += 32) {
    __syncthreads();
    int c = tid;
    for (int l = 0; l < 2; ++l, c += 256) {
      int row = c >> 3, kq = (c & 7) * 4;
      int rg = bt0 + row; if (rg > 2046) rg = 2046;   // clamp tail loads
      float4 x4 = *(const float4*)&pe[(size_t)rg * 256 + k0 + kq];
      Xs[kq + 0][row] = x4.x; Xs[kq + 1][row] = x4.y;
      Xs[kq + 2][row] = x4.z; Xs[kq + 3][row] = x4.w;
    }
    c = tid;
    for (int l = 0; l < 2; ++l, c += 256) {
      int row = c >> 3, kq = (c & 7) * 4;
      float4 w4 = *(const float4*)&Wp[(size_t)(c0 + row) * 256 + k0 + kq];
      Ws[kq + 0][row] = w4.x; Ws[kq + 1][row] = w4.y;
      Ws[kq + 2][row] = w4.z; Ws[kq + 3][row] = w4.w;
    }
    __syncthreads();
#pragma unroll
    for (int kk = 0; kk < 32; ++kk) {
      float4 a4 = *(const float4*)&Xs[kk][ty * 4];
      float4 b4 = *(const float4*)&Ws[kk][tx * 4];
      float av[4] = {a4.x, a4.y, a4.z, a4.w};
      float bv_[4] = {b4.x, b4.y, b4.z, b4.w};
#pragma unroll
      for (int i = 0; i < 4; ++i)
#pragma unroll
        for (int j = 0; j < 4; ++j) acc[i][j] += av[i] * bv_[j];
    }
  }
#pragma unroll
  for (int j = 0; j < 4; ++j) {
    int dcol = c0 + tx * 4 + j;
    int h = dcol >> 5, dd = dcol & 31;
#pragma unroll
    for (int i = 0; i < 4; ++i) {
      int r = bt0 + ty * 4 + i;
      if (r < NREL) pbuf[((size_t)h * NREL + r) * DHEAD + dd] = acc[i][j];
    }
  }
}

// ---------------------------------------------------------------------------
// Fused attention: one block per (b,h, 16-row i-tile). grid 4096, block 256.
// Pass A: raw S=(qu.k + qv.P[i-j+1023]) -> global (attn area), track row max.
// Pass B1: exp/sum/normalize in place. Pass B2: AV -> o_buf.
__global__ __launch_bounds__(256) void attn_kernel(
    const float* __restrict__ qbuf, const float* __restrict__ kbuf, const float* __restrict__ vbuf,
    const float* __restrict__ pbuf, const float* __restrict__ ub, const float* __restrict__ vbias,
    float* __restrict__ attn_out, float* __restrict__ obuf)
{
  __shared__ float qu_s[16][36];
  __shared__ float qv_s[16][36];
  __shared__ float k_s[128][36];    // K tile in pass A, V tile in pass B2
  __shared__ float P_s[144][36];    // P window in pass A, attn tile (16x132) in B2
  __shared__ float m_s[16];

  const int blk = blockIdx.x;
  const int bh = blk >> 6;          // 0..63
  const int it = blk & 63;
  const int i0 = it << 4;
  const int h = bh & 7;
  const int tid = threadIdx.x;
  const float* qrow = qbuf + (size_t)bh * TSEQ * DHEAD;
  const float* krow = kbuf + (size_t)bh * TSEQ * DHEAD;
  const float* vrow = vbuf + (size_t)bh * TSEQ * DHEAD;
  const float* Ph   = pbuf + (size_t)h * NREL * DHEAD;
  float* arow = attn_out + (size_t)bh * TSEQ * TSEQ;

  if (tid < 128) {
    int ri = tid >> 3, dq = (tid & 7) * 4;
    float4 q4 = *(const float4*)&qrow[(size_t)(i0 + ri) * DHEAD + dq];
    float4 u4 = *(const float4*)&ub[h * DHEAD + dq];
    float4 w4 = *(const float4*)&vbias[h * DHEAD + dq];
    qu_s[ri][dq + 0] = q4.x + u4.x;  qu_s[ri][dq + 1] = q4.y + u4.y;
    qu_s[ri][dq + 2] = q4.z + u4.z;  qu_s[ri][dq + 3] = q4.w + u4.w;
    qv_s[ri][dq + 0] = q4.x + w4.x;  qv_s[ri][dq + 1] = q4.y + w4.y;
    qv_s[ri][dq + 2] = q4.z + w4.z;  qv_s[ri][dq + 3] = q4.w + w4.w;
  }

  const int tx = tid & 31;
  const int ty = tid >> 5;          // 0..7
  const int ri0 = ty * 2;
  float m_run0 = -1e30f, m_run1 = -1e30f;

  // ---- Pass A: raw scores + row max ----
  for (int jt = 0; jt < 8; ++jt) {
    const int j0 = jt * 128;
    __syncthreads();
    for (int c = tid; c < 1024; c += 256) {          // K tile 128x32
      int jj = c >> 3, dq = (c & 7) * 4;
      *(float4*)&k_s[jj][dq] = *(const float4*)&krow[(size_t)(j0 + jj) * DHEAD + dq];
    }
    const int rmin = i0 - j0 + 896;                  // P rows rmin..rmin+142, always in [0,2046]
    for (int c = tid; c < 143 * 8; c += 256) {
      int rl = c >> 3, dq = (c & 7) * 4;
      *(float4*)&P_s[rl][dq] = *(const float4*)&Ph[(size_t)(rmin + rl) * DHEAD + dq];
    }
    __syncthreads();

    float acc[2][4] = {};
#pragma unroll
    for (int d0 = 0; d0 < 32; d0 += 4) {
      float4 quA = *(const float4*)&qu_s[ri0][d0];
      float4 quB = *(const float4*)&qu_s[ri0 + 1][d0];
      float4 qvA = *(const float4*)&qv_s[ri0][d0];
      float4 qvB = *(const float4*)&qv_s[ri0 + 1][d0];
#pragma unroll
      for (int x = 0; x < 4; ++x) {
        int jj = tx + 32 * x;
        float4 k4 = *(const float4*)&k_s[jj][d0];
        int rlA = ri0 + 127 - jj;                    // rloc for row ri0; row ri0+1 is rlA+1
        float4 pA = *(const float4*)&P_s[rlA][d0];
        float4 pB = *(const float4*)&P_s[rlA + 1][d0];
        acc[0][x] += quA.x * k4.x + quA.y * k4.y + quA.z * k4.z + quA.w * k4.w
                   + qvA.x * pA.x + qvA.y * pA.y + qvA.z * pA.z + qvA.w * pA.w;
        acc[1][x] += quB.x * k4.x + quB.y * k4.y + quB.z * k4.z + quB.w * k4.w
                   + qvB.x * pB.x + qvB.y * pB.y + qvB.z * pB.z + qvB.w * pB.w;
      }
    }
    float mt0 = fmaxf(fmaxf(acc[0][0], acc[0][1]), fmaxf(acc[0][2], acc[0][3]));
    float mt1 = fmaxf(fmaxf(acc[1][0], acc[1][1]), fmaxf(acc[1][2], acc[1][3]));
#pragma unroll
    for (int off = 16; off > 0; off >>= 1) {
      mt0 = fmaxf(mt0, __shfl_xor(mt0, off, 32));
      mt1 = fmaxf(mt1, __shfl_xor(mt1, off, 32));
    }
    m_run0 = fmaxf(m_run0, mt0);
    m_run1 = fmaxf(m_run1, mt1);
    float* ar0 = &arow[(size_t)(i0 + ri0) * TSEQ + j0];
    float* ar1 = &arow[(size_t)(i0 + ri0 + 1) * TSEQ + j0];
#pragma unroll
    for (int x = 0; x < 4; ++x) {
      ar0[tx + 32 * x] = acc[0][x];
      ar1[tx + 32 * x] = acc[1][x];
    }
  }
  if (tx == 0) { m_s[ri0] = m_run0; m_s[ri0 + 1] = m_run1; }
  __threadfence_block();
  __syncthreads();

  // ---- Pass B1: softmax normalize in place ----
  {
    const float kscale = (float)(1.0 / (16.0 * 0.69314718055994530942)); // 1/(sqrt(D)*ln2)
    int rw = tid >> 4, u = tid & 15;
    float m = m_s[rw];
    float* ar = &arow[(size_t)(i0 + rw) * TSEQ];
    float sum = 0.f;
#pragma unroll 4
    for (int c = 0; c < 16; ++c) {
      float4 s4 = *(const float4*)&ar[c * 64 + u * 4];
      sum += exp2f((s4.x - m) * kscale) + exp2f((s4.y - m) * kscale)
           + exp2f((s4.z - m) * kscale) + exp2f((s4.w - m) * kscale);
    }
#pragma unroll
    for (int off = 8; off > 0; off >>= 1) sum += __shfl_xor(sum, off, 16);
    float rcpl = 1.0f / sum;
#pragma unroll 4
    for (int c = 0; c < 16; ++c) {
      float4 s4 = *(const float4*)&ar[c * 64 + u * 4];
      float4 a4;
      a4.x = exp2f((s4.x - m) * kscale) * rcpl;
      a4.y = exp2f((s4.y - m) * kscale) * rcpl;
      a4.z = exp2f((s4.z - m) * kscale) * rcpl;
      a4.w = exp2f((s4.w - m) * kscale) * rcpl;
      *(float4*)&ar[c * 64 + u * 4] = a4;
    }
  }
  __threadfence_block();

  // ---- Pass B2: out_head = attn @ v ----
  float* At = &P_s[0][0];           // At[16][132] (2112 floats <= 5184)
  const int d = tid & 31;
  const int rg = tid >> 5;          // 0..7 -> rows rg*2, rg*2+1
  float oacc0 = 0.f, oacc1 = 0.f;
  for (int vt = 0; vt < 8; ++vt) {
    const int j0 = vt * 128;
    __syncthreads();
    for (int c = tid; c < 1024; c += 256) {          // V tile 128x32
      int jj = c >> 3, dq = (c & 7) * 4;
      *(float4*)&k_s[jj][dq] = *(const float4*)&vrow[(size_t)(j0 + jj) * DHEAD + dq];
    }
    for (int c = tid; c < 512; c += 256) {           // attn tile 16x128
      int rr = c >> 5, jq = (c & 31) * 4;
      *(float4*)&At[rr * 132 + jq] = *(const float4*)&arow[(size_t)(i0 + rr) * TSEQ + j0 + jq];
    }
    __syncthreads();
#pragma unroll 4
    for (int jj = 0; jj < 128; jj += 4) {
      float4 a0 = *(const float4*)&At[(rg * 2 + 0) * 132 + jj];
      float4 a1 = *(const float4*)&At[(rg * 2 + 1) * 132 + jj];
      float v0 = k_s[jj + 0][d], v1 = k_s[jj + 1][d], v2 = k_s[jj + 2][d], v3 = k_s[jj + 3][d];
      oacc0 += a0.x * v0 + a0.y * v1 + a0.z * v2 + a0.w * v3;
      oacc1 += a1.x * v0 + a1.y * v1 + a1.z * v2 + a1.w * v3;
    }
  }
  const int b = bh >> 3;
  obuf[((size_t)b * TSEQ + i0 + rg * 2 + 0) * DMODEL + h * DHEAD + d] = oacc0;
  obuf[((size_t)b * TSEQ + i0 + rg * 2 + 1) * DMODEL + h * DHEAD + d] = oacc1;
}

// ---------------------------------------------------------------------------
// Output projection: out[bt][c] = sum_k o[bt][k]*Wo[c][k] + bo[c]; grid (128,4)
__global__ __launch_bounds__(256) void oproj_kernel(
    const float* __restrict__ A, const float* __restrict__ Wo, const float* __restrict__ bo,
    float* __restrict__ out)
{
  __shared__ float Xs[32][68];
  __shared__ float Ws[32][68];
  const int bm = blockIdx.x;
  const int bn = blockIdx.y;
  const int c0  = bn * 64;
  const int bt0 = bm * 64;
  const int tid = threadIdx.x;
  const int tx = tid & 15, ty = tid >> 4;
  float acc[4][4] = {};

  for (int k0 = 0; k0 < 256; k0 += 32) {
    __syncthreads();
    int c = tid;
    for (int l = 0; l < 2; ++l, c += 256) {
      int row = c >> 3, kq = (c & 7) * 4;
      float4 x4 = *(const float4*)&A[(size_t)(bt0 + row) * 256 + k0 + kq];
      Xs[kq + 0][row] = x4.x; Xs[kq + 1][row] = x4.y;
      Xs[kq + 2][row] = x4.z; Xs[kq + 3][row] = x4.w;
    }
    c = tid;
    for (int l = 0; l < 2; ++l, c += 256) {
      int row = c >> 3, kq = (c & 7) * 4;
      float4 w4 = *(const float4*)&Wo[(size_t)(c0 + row) * 256 + k0 + kq];
      Ws[kq + 0][row] = w4.x; Ws[kq + 1][row] = w4.y;
      Ws[kq + 2][row] = w4.z; Ws[kq + 3][row] = w4.w;
    }
    __syncthreads();
#pragma unroll
    for (int kk = 0; kk < 32; ++kk) {
      float4 a4 = *(const float4*)&Xs[kk][ty * 4];
      float4 b4 = *(const float4*)&Ws[kk][tx * 4];
      float av[4] = {a4.x, a4.y, a4.z, a4.w};
      float bv_[4] = {b4.x, b4.y, b4.z, b4.w};
#pragma unroll
      for (int i = 0; i < 4; ++i)
#pragma unroll
        for (int j = 0; j < 4; ++j) acc[i][j] += av[i] * bv_[j];
    }
  }
#pragma unroll
  for (int j = 0; j < 4; ++j) {
    int dcol = c0 + tx * 4 + j;
    float bz = bo[dcol];
#pragma unroll
    for (int i = 0; i < 4; ++i) {
      int bt = bt0 + ty * 4 + i;
      out[(size_t)bt * DMODEL + dcol] = acc[i][j] + bz;
    }
  }
}

// ---------------------------------------------------------------------------
extern "C" void kernel_launch(void* const* d_in, const int* in_sizes, int n_in,
                              void* d_out, int out_size, void* d_ws, size_t ws_size,
                              hipStream_t stream) {
  const float* X   = (const float*)d_in[0];   // query [B,T,D]
  const float* Wq  = (const float*)d_in[1];
  const float* bq  = (const float*)d_in[2];
  const float* Wk  = (const float*)d_in[3];
  const float* bk  = (const float*)d_in[4];
  const float* Wv  = (const float*)d_in[5];
  const float* bv  = (const float*)d_in[6];
  const float* Wp  = (const float*)d_in[7];
  const float* Wo  = (const float*)d_in[8];
  const float* bo  = (const float*)d_in[9];
  const float* ub  = (const float*)d_in[10];  // u_bias [H,DH]
  const float* vbb = (const float*)d_in[11];  // v_bias [H,DH]

  float* ws = (float*)d_ws;                   // needs 37.75 MB
  float* qbuf = ws + Q_OFF;
  float* kbuf = ws + K_OFF;
  float* vbuf = ws + V_OFF;
  float* pbuf = ws + P_OFF;
  float* obuf = ws + O_OFF;
  float* pe   = ws + PE_OFF;

  float* out0 = (float*)d_out;                // [B,T,D]
  float* attn = out0 + OUT0;                  // [B,H,T,T]

  pe_kernel<<<2047, 256, 0, stream>>>(pe);
  proj_qkv_kernel<<<dim3(128, 12), 256, 0, stream>>>(X, Wq, Wk, Wv, bq, bk, bv,
                                                     qbuf, kbuf, vbuf);
  pgemm_kernel<<<dim3(32, 4), 256, 0, stream>>>(pe, Wp, pbuf);
  attn_kernel<<<4096, 256, 0, stream>>>(qbuf, kbuf, vbuf, pbuf, ub, vbb, attn, obuf);
  oproj_kernel<<<dim3(128, 4), 256, 0, stream>>>(obuf, Wo, bo, out0);
}

// Round 2
// 647.505 us; speedup vs baseline: 1.4661x; 1.4661x over previous
//
#include <hip/hip_runtime.h>
#include <math.h>

// Problem constants
#define TSEQ   1024
#define DMODEL 256
#define NHEAD  8
#define DHEAD  32
#define NREL   2047
#define OUT0   2097152   // B*T*D elements (output 0 size)

// workspace offsets (floats); total = 9,436,672 floats = 37.75 MB
#define Q_OFF   0u
#define K_OFF   2097152u
#define V_OFF   4194304u
#define P_OFF   6291456u
#define O_OFF   6815488u
#define PE_OFF  8912640u

// ---------------------------------------------------------------------------
// Sinusoidal relative PE table, fp32 (fp64 trig was soft-float and slow).
// pe[r][col], r=0..2046 (pos=r-1023); even col=sin, odd col=cos.
__global__ __launch_bounds__(256) void pe_kernel(float* __restrict__ pe) {
  int idx = blockIdx.x * 256 + threadIdx.x;
  int r = idx >> 8;
  int col = idx & 255;
  int m2 = col >> 1;
  // denom = 10000^(-m/128) = 2^(-m * log2(1e4)/128)
  float denom = exp2f((float)m2 * -0.10381025296523007f);
  float ang = (float)(r - 1023) * denom;
  pe[idx] = (col & 1) ? cosf(ang) : sinf(ang);
}

// ---------------------------------------------------------------------------
// QKV projection (unchanged from R1)
__global__ __launch_bounds__(256) void proj_qkv_kernel(
    const float* __restrict__ X,
    const float* __restrict__ Wq, const float* __restrict__ Wk, const float* __restrict__ Wv,
    const float* __restrict__ bq, const float* __restrict__ bk, const float* __restrict__ bv,
    float* __restrict__ qbuf, float* __restrict__ kbuf, float* __restrict__ vbuf)
{
  __shared__ float Xs[32][68];
  __shared__ float Ws[32][68];
  const int bm = blockIdx.x;
  const int bn = blockIdx.y;
  const int sel = bn >> 2;
  const float* W   = sel == 0 ? Wq : (sel == 1 ? Wk : Wv);
  const float* bia = sel == 0 ? bq : (sel == 1 ? bk : bv);
  float* dst       = sel == 0 ? qbuf : (sel == 1 ? kbuf : vbuf);
  const int c0  = (bn & 3) * 64;
  const int bt0 = bm * 64;
  const int tid = threadIdx.x;
  const int tx = tid & 15, ty = tid >> 4;
  float acc[4][4] = {};

  for (int k0 = 0; k0 < 256; k0 += 32) {
    __syncthreads();
    int c = tid;
    for (int l = 0; l < 2; ++l, c += 256) {
      int row = c >> 3, kq = (c & 7) * 4;
      float4 x4 = *(const float4*)&X[(size_t)(bt0 + row) * 256 + k0 + kq];
      Xs[kq + 0][row] = x4.x; Xs[kq + 1][row] = x4.y;
      Xs[kq + 2][row] = x4.z; Xs[kq + 3][row] = x4.w;
    }
    c = tid;
    for (int l = 0; l < 2; ++l, c += 256) {
      int row = c >> 3, kq = (c & 7) * 4;
      float4 w4 = *(const float4*)&W[(size_t)(c0 + row) * 256 + k0 + kq];
      Ws[kq + 0][row] = w4.x; Ws[kq + 1][row] = w4.y;
      Ws[kq + 2][row] = w4.z; Ws[kq + 3][row] = w4.w;
    }
    __syncthreads();
#pragma unroll
    for (int kk = 0; kk < 32; ++kk) {
      float4 a4 = *(const float4*)&Xs[kk][ty * 4];
      float4 b4 = *(const float4*)&Ws[kk][tx * 4];
      float av[4] = {a4.x, a4.y, a4.z, a4.w};
      float bv_[4] = {b4.x, b4.y, b4.z, b4.w};
#pragma unroll
      for (int i = 0; i < 4; ++i)
#pragma unroll
        for (int j = 0; j < 4; ++j) acc[i][j] += av[i] * bv_[j];
    }
  }
#pragma unroll
  for (int j = 0; j < 4; ++j) {
    int dcol = c0 + tx * 4 + j;
    float bz = bia[dcol];
    int hh = dcol >> 5, dd = dcol & 31;
#pragma unroll
    for (int i = 0; i < 4; ++i) {
      int bt = bt0 + ty * 4 + i;
      int bb = bt >> 10, t = bt & 1023;
      dst[(((size_t)bb * NHEAD + hh) * TSEQ + t) * DHEAD + dd] = acc[i][j] + bz;
    }
  }
}

// ---------------------------------------------------------------------------
// P projection (unchanged from R1): stores [H][NREL][DH]
__global__ __launch_bounds__(256) void pgemm_kernel(
    const float* __restrict__ pe, const float* __restrict__ Wp, float* __restrict__ pbuf)
{
  __shared__ float Xs[32][68];
  __shared__ float Ws[32][68];
  const int bm = blockIdx.x;
  const int bn = blockIdx.y;
  const int c0  = bn * 64;
  const int bt0 = bm * 64;
  const int tid = threadIdx.x;
  const int tx = tid & 15, ty = tid >> 4;
  float acc[4][4] = {};

  for (int k0 = 0; k0 < 256; k0 += 32) {
    __syncthreads();
    int c = tid;
    for (int l = 0; l < 2; ++l, c += 256) {
      int row = c >> 3, kq = (c & 7) * 4;
      int rgg = bt0 + row; if (rgg > 2046) rgg = 2046;
      float4 x4 = *(const float4*)&pe[(size_t)rgg * 256 + k0 + kq];
      Xs[kq + 0][row] = x4.x; Xs[kq + 1][row] = x4.y;
      Xs[kq + 2][row] = x4.z; Xs[kq + 3][row] = x4.w;
    }
    c = tid;
    for (int l = 0; l < 2; ++l, c += 256) {
      int row = c >> 3, kq = (c & 7) * 4;
      float4 w4 = *(const float4*)&Wp[(size_t)(c0 + row) * 256 + k0 + kq];
      Ws[kq + 0][row] = w4.x; Ws[kq + 1][row] = w4.y;
      Ws[kq + 2][row] = w4.z; Ws[kq + 3][row] = w4.w;
    }
    __syncthreads();
#pragma unroll
    for (int kk = 0; kk < 32; ++kk) {
      float4 a4 = *(const float4*)&Xs[kk][ty * 4];
      float4 b4 = *(const float4*)&Ws[kk][tx * 4];
      float av[4] = {a4.x, a4.y, a4.z, a4.w};
      float bv_[4] = {b4.x, b4.y, b4.z, b4.w};
#pragma unroll
      for (int i = 0; i < 4; ++i)
#pragma unroll
        for (int j = 0; j < 4; ++j) acc[i][j] += av[i] * bv_[j];
    }
  }
#pragma unroll
  for (int j = 0; j < 4; ++j) {
    int dcol = c0 + tx * 4 + j;
    int hh = dcol >> 5, dd = dcol & 31;
#pragma unroll
    for (int i = 0; i < 4; ++i) {
      int rr = bt0 + ty * 4 + i;
      if (rr < NREL) pbuf[((size_t)hh * NREL + rr) * DHEAD + dd] = acc[i][j];
    }
  }
}

// ---------------------------------------------------------------------------
// Fused attention v2: one block per (b,h, 16-row i-tile). grid 4096, block 256.
// Sweep 1 (j-tiles descending): combined outer-product GEMM — half the lanes
//   compute content S-tile (qu·k), half compute an M-chunk (qv·P) into a
//   3-slot LDS ring; content lanes then gather pos = M[i, i-j+1023] from the
//   ring and the S strip is parked in registers (64 floats/thread) via an LDS
//   redistribution (in the ring's dead slot).
// Softmax: per-row max/sum via 16-lane shuffles (strip rows = 16 threads).
// Sweep 2 (ascending): exp'd probs written to global attn ONCE + staged in
//   LDS; AV as register-blocked (4 rows x 8 d) accumulation; final 16-way
//   j-partial reduction through LDS.
__global__ __launch_bounds__(256, 2) void attn_kernel(
    const float* __restrict__ qbuf, const float* __restrict__ kbuf, const float* __restrict__ vbuf,
    const float* __restrict__ pbuf, const float* __restrict__ ub, const float* __restrict__ vbias,
    float* __restrict__ attn_out, float* __restrict__ obuf)
{
  __shared__ float smem[15744];            // 62.98 KB (2 blocks/CU)
  float* const quT = smem;                 // [32][20] transposed q+u
  float* const qvT = smem + 640;           // [32][20] transposed q+v
  float* const BT  = smem + 1280;          // [32][260]: cols 0..127 kT, 128..255 PT
  float* const MR  = smem + 9600;          // 3 ring slots of [16][128]

  const int blk = blockIdx.x;
  const int bh  = blk >> 6;
  const int i0  = (blk & 63) << 4;
  const int h   = bh & 7;
  const int bb  = bh >> 3;
  const int tid = threadIdx.x;

  const float* __restrict__ qrow = qbuf + (size_t)bh * (TSEQ * DHEAD);
  const float* __restrict__ krow = kbuf + (size_t)bh * (TSEQ * DHEAD);
  const float* __restrict__ vrow = vbuf + (size_t)bh * (TSEQ * DHEAD);
  const float* __restrict__ Ph   = pbuf + (size_t)h * ((size_t)NREL * DHEAD);
  float* __restrict__ arow = attn_out + (size_t)bh * ((size_t)TSEQ * TSEQ);

  // ---- stage qu/qv transposed ----
  if (tid < 128) {
    const int ri = tid >> 3, dq = (tid & 7) * 4;
    const float4 q4 = *(const float4*)&qrow[(size_t)(i0 + ri) * DHEAD + dq];
    const float4 u4 = *(const float4*)&ub[h * DHEAD + dq];
    const float4 w4 = *(const float4*)&vbias[h * DHEAD + dq];
    quT[(dq + 0) * 20 + ri] = q4.x + u4.x;
    quT[(dq + 1) * 20 + ri] = q4.y + u4.y;
    quT[(dq + 2) * 20 + ri] = q4.z + u4.z;
    quT[(dq + 3) * 20 + ri] = q4.w + u4.w;
    qvT[(dq + 0) * 20 + ri] = q4.x + w4.x;
    qvT[(dq + 1) * 20 + ri] = q4.y + w4.y;
    qvT[(dq + 2) * 20 + ri] = q4.z + w4.z;
    qvT[(dq + 3) * 20 + ri] = q4.w + w4.w;
  }

  const int rg   = tid >> 6;               // wave id -> rows rg*4..rg*4+3
  const int cg   = tid & 63;               // combined column group (x4)
  const bool isM = (cg >= 32);
  const int bcol = cg * 4;                 // BT column base (0..255)
  const float* const Aptr = (isM ? qvT : quT) + rg * 4;

  const int lr    = tid >> 1;              // loader row 0..127
  const int lhalf = (tid & 1) * 16;        // float offset within 32-float row

  float s[64];                             // register-resident S strip slice

  // ---------------- pre-phase: M chunks 0,1 ----------------
  {
#pragma unroll
    for (int seg = 0; seg < 2; ++seg) {
      const int g = i0 + seg * 128 + lr;   // <= 1263, always in range
      const float* src = &Ph[(size_t)g * DHEAD + lhalf];
      const int col = seg * 128 + lr;
#pragma unroll
      for (int l = 0; l < 4; ++l) {
        const float4 x = *(const float4*)&src[l * 4];
        const int dq = lhalf + l * 4;
        BT[(dq + 0) * 260 + col] = x.x;
        BT[(dq + 1) * 260 + col] = x.y;
        BT[(dq + 2) * 260 + col] = x.z;
        BT[(dq + 3) * 260 + col] = x.w;
      }
    }
    __syncthreads();
    float acc[4][4] = {};
    const float* Apre = qvT + rg * 4;
#pragma unroll 8
    for (int kk = 0; kk < 32; ++kk) {
      const float4 a4 = *(const float4*)&Apre[kk * 20];
      const float4 b4 = *(const float4*)&BT[kk * 260 + bcol];
      const float av[4] = {a4.x, a4.y, a4.z, a4.w};
      const float bw[4] = {b4.x, b4.y, b4.z, b4.w};
#pragma unroll
      for (int rr = 0; rr < 4; ++rr)
#pragma unroll
        for (int jj = 0; jj < 4; ++jj) acc[rr][jj] += av[rr] * bw[jj];
    }
    float* const Md = MR + (cg >> 5) * 2048 + (cg & 31) * 4;
#pragma unroll
    for (int rr = 0; rr < 4; ++rr)
      *(float4*)&Md[(rg * 4 + rr) * 128] =
          make_float4(acc[rr][0], acc[rr][1], acc[rr][2], acc[rr][3]);
    __syncthreads();
  }

  // ---------------- sweep 1: j-tiles descending ----------------
#pragma unroll
  for (int t = 7; t >= 0; --t) {
    const int j0 = t * 128;
    const int cnext = 9 - t;               // M chunk computed this phase
    // stage kT tile + PT chunk into BT (transposed scatter)
    {
      const float* srck = &krow[(size_t)(j0 + lr) * DHEAD + lhalf];
      int g = i0 + cnext * 128 + lr;
      if (g > 2046) g = 2046;              // chunk 9 is garbage, never gathered
      const float* srcp = &Ph[(size_t)g * DHEAD + lhalf];
#pragma unroll
      for (int l = 0; l < 4; ++l) {
        const float4 xk = *(const float4*)&srck[l * 4];
        const float4 xp = *(const float4*)&srcp[l * 4];
        const int dq = lhalf + l * 4;
        BT[(dq + 0) * 260 + lr] = xk.x;
        BT[(dq + 1) * 260 + lr] = xk.y;
        BT[(dq + 2) * 260 + lr] = xk.z;
        BT[(dq + 3) * 260 + lr] = xk.w;
        BT[(dq + 0) * 260 + 128 + lr] = xp.x;
        BT[(dq + 1) * 260 + 128 + lr] = xp.y;
        BT[(dq + 2) * 260 + 128 + lr] = xp.z;
        BT[(dq + 3) * 260 + 128 + lr] = xp.w;
      }
    }
    __syncthreads();                       // #1
    float acc[4][4] = {};
#pragma unroll 8
    for (int kk = 0; kk < 32; ++kk) {
      const float4 a4 = *(const float4*)&Aptr[kk * 20];
      const float4 b4 = *(const float4*)&BT[kk * 260 + bcol];
      const float av[4] = {a4.x, a4.y, a4.z, a4.w};
      const float bw[4] = {b4.x, b4.y, b4.z, b4.w};
#pragma unroll
      for (int rr = 0; rr < 4; ++rr)
#pragma unroll
        for (int jj = 0; jj < 4; ++jj) acc[rr][jj] += av[rr] * bw[jj];
    }
    if (isM) {
      float* const Md = MR + (cnext % 3) * 2048 + (cg & 31) * 4;
#pragma unroll
      for (int rr = 0; rr < 4; ++rr)
        *(float4*)&Md[(rg * 4 + rr) * 128] =
            make_float4(acc[rr][0], acc[rr][1], acc[rr][2], acc[rr][3]);
    } else {
      const float* const Mlo = MR + ((7 - t) % 3) * 2048;
      const float* const Mhi = MR + ((8 - t) % 3) * 2048;
      const int thr  = (8 - t) * 128;
      const int rbas = rg * 4 - bcol + 1023 - j0;
#pragma unroll
      for (int rr = 0; rr < 4; ++rr) {
        const int i = rg * 4 + rr;
#pragma unroll
        for (int jj = 0; jj < 4; ++jj) {
          const int rl = rbas + rr - jj;
          const float* Mp = (rl >= thr) ? Mhi : Mlo;
          acc[rr][jj] += Mp[i * 128 + (rl & 127)];
        }
      }
    }
    __syncthreads();                       // #2 (gather done before Sx reuse)
    float* const Sx = MR + ((7 - t) % 3) * 2048;   // dead ring slot
    if (!isM) {
#pragma unroll
      for (int rr = 0; rr < 4; ++rr) {
        const int i = rg * 4 + rr;
        const int colb = (bcol + 4 * i) & 127;     // swizzle vs bank camping
        *(float4*)&Sx[i * 128 + colb] =
            make_float4(acc[rr][0], acc[rr][1], acc[rr][2], acc[rr][3]);
      }
    }
    __syncthreads();                       // #3
    {
      const int rr2 = tid >> 4, u2 = tid & 15;
#pragma unroll
      for (int k2 = 0; k2 < 2; ++k2) {
        const int colb = ((u2 * 8 + k2 * 4) + 4 * rr2) & 127;
        const float4 v4 = *(const float4*)&Sx[rr2 * 128 + colb];
        s[t * 8 + k2 * 4 + 0] = v4.x;
        s[t * 8 + k2 * 4 + 1] = v4.y;
        s[t * 8 + k2 * 4 + 2] = v4.z;
        s[t * 8 + k2 * 4 + 3] = v4.w;
      }
    }
  }

  // ---------------- softmax (rows = 16-lane groups) ----------------
  const int r  = tid >> 4;                 // strip row 0..15
  const int u2 = tid & 15;                 // 8-col group within row
  float mx = -1e30f;
#pragma unroll
  for (int k = 0; k < 64; ++k) mx = fmaxf(mx, s[k]);
  mx = fmaxf(mx, __shfl_xor(mx, 1));
  mx = fmaxf(mx, __shfl_xor(mx, 2));
  mx = fmaxf(mx, __shfl_xor(mx, 4));
  mx = fmaxf(mx, __shfl_xor(mx, 8));
  const float ksc = 0.09016844136f;        // 1/(sqrt(256)*ln2)
  float sum = 0.f;
#pragma unroll
  for (int k = 0; k < 64; ++k) {
    const float p = exp2f((s[k] - mx) * ksc);
    s[k] = p;
    sum += p;
  }
  sum += __shfl_xor(sum, 1);
  sum += __shfl_xor(sum, 2);
  sum += __shfl_xor(sum, 4);
  sum += __shfl_xor(sum, 8);
  const float rcpl = 1.0f / sum;

  // ---------------- sweep 2: attn write + AV ----------------
  float* const Vs = BT;                    // [128][34] (b64 granule)
  float* const Px = MR;                    // slot 0, [16][128] swizzled
  const int rq   = tid >> 6;               // wave -> 4 rows rq*4..+3
  const int dsec = (tid >> 4) & 3;         // 8-wide d section
  const int uu   = tid & 15;               // j mod 16
  float oa[4][8] = {};

#pragma unroll
  for (int t2 = 0; t2 < 8; ++t2) {
    const int j0 = t2 * 128;
    __syncthreads();
#pragma unroll
    for (int l = 0; l < 4; ++l) {
      const int idx = tid + 256 * l;
      const int row = idx >> 3, dq = (idx & 7) * 4;
      const float4 v4 = *(const float4*)&vrow[(size_t)(j0 + row) * DHEAD + dq];
      *(float2*)&Vs[row * 34 + dq]     = make_float2(v4.x, v4.y);
      *(float2*)&Vs[row * 34 + dq + 2] = make_float2(v4.z, v4.w);
    }
    {
      float pv[8];
#pragma unroll
      for (int k = 0; k < 8; ++k) pv[k] = s[t2 * 8 + k] * rcpl;
      float* gp = &arow[(size_t)(i0 + r) * TSEQ + j0 + u2 * 8];
      *(float4*)&gp[0] = make_float4(pv[0], pv[1], pv[2], pv[3]);
      *(float4*)&gp[4] = make_float4(pv[4], pv[5], pv[6], pv[7]);
      const int c0b = ((u2 * 8)     + 4 * r) & 127;
      const int c1b = ((u2 * 8 + 4) + 4 * r) & 127;
      *(float4*)&Px[r * 128 + c0b] = make_float4(pv[0], pv[1], pv[2], pv[3]);
      *(float4*)&Px[r * 128 + c1b] = make_float4(pv[4], pv[5], pv[6], pv[7]);
    }
    __syncthreads();
#pragma unroll
    for (int jj = 0; jj < 8; ++jj) {
      const int j = uu + 16 * jj;
      float pr[4];
#pragma unroll
      for (int rr = 0; rr < 4; ++rr) {
        const int i = rq * 4 + rr;
        pr[rr] = Px[i * 128 + ((j + 4 * i) & 127)];
      }
      float vv[8];
#pragma unroll
      for (int k2 = 0; k2 < 4; ++k2)
        *(float2*)&vv[k2 * 2] = *(const float2*)&Vs[j * 34 + dsec * 8 + k2 * 2];
#pragma unroll
      for (int rr = 0; rr < 4; ++rr)
#pragma unroll
        for (int dd = 0; dd < 8; ++dd)
          oa[rr][dd] += pr[rr] * vv[dd];
    }
  }

  // reduce 16-way j-partials through LDS, write o_head
  __syncthreads();
  float* const part = BT;                  // stride 516 to spread banks
#pragma unroll
  for (int rr = 0; rr < 4; ++rr) {
    const int i = rq * 4 + rr;
    float* dst = &part[uu * 516 + i * 32 + dsec * 8];
    *(float4*)&dst[0] = make_float4(oa[rr][0], oa[rr][1], oa[rr][2], oa[rr][3]);
    *(float4*)&dst[4] = make_float4(oa[rr][4], oa[rr][5], oa[rr][6], oa[rr][7]);
  }
  __syncthreads();
#pragma unroll
  for (int w2 = 0; w2 < 2; ++w2) {
    const int o = tid + 256 * w2;
    float v = 0.f;
#pragma unroll
    for (int u3 = 0; u3 < 16; ++u3) v += part[u3 * 516 + o];
    const int orow = o >> 5, od = o & 31;
    obuf[((size_t)bb * TSEQ + i0 + orow) * DMODEL + h * DHEAD + od] = v;
  }
}

// ---------------------------------------------------------------------------
// Output projection (unchanged from R1)
__global__ __launch_bounds__(256) void oproj_kernel(
    const float* __restrict__ A, const float* __restrict__ Wo, const float* __restrict__ bo,
    float* __restrict__ out)
{
  __shared__ float Xs[32][68];
  __shared__ float Ws[32][68];
  const int bm = blockIdx.x;
  const int bn = blockIdx.y;
  const int c0  = bn * 64;
  const int bt0 = bm * 64;
  const int tid = threadIdx.x;
  const int tx = tid & 15, ty = tid >> 4;
  float acc[4][4] = {};

  for (int k0 = 0; k0 < 256; k0 += 32) {
    __syncthreads();
    int c = tid;
    for (int l = 0; l < 2; ++l, c += 256) {
      int row = c >> 3, kq = (c & 7) * 4;
      float4 x4 = *(const float4*)&A[(size_t)(bt0 + row) * 256 + k0 + kq];
      Xs[kq + 0][row] = x4.x; Xs[kq + 1][row] = x4.y;
      Xs[kq + 2][row] = x4.z; Xs[kq + 3][row] = x4.w;
    }
    c = tid;
    for (int l = 0; l < 2; ++l, c += 256) {
      int row = c >> 3, kq = (c & 7) * 4;
      float4 w4 = *(const float4*)&Wo[(size_t)(c0 + row) * 256 + k0 + kq];
      Ws[kq + 0][row] = w4.x; Ws[kq + 1][row] = w4.y;
      Ws[kq + 2][row] = w4.z; Ws[kq + 3][row] = w4.w;
    }
    __syncthreads();
#pragma unroll
    for (int kk = 0; kk < 32; ++kk) {
      float4 a4 = *(const float4*)&Xs[kk][ty * 4];
      float4 b4 = *(const float4*)&Ws[kk][tx * 4];
      float av[4] = {a4.x, a4.y, a4.z, a4.w};
      float bv_[4] = {b4.x, b4.y, b4.z, b4.w};
#pragma unroll
      for (int i = 0; i < 4; ++i)
#pragma unroll
        for (int j = 0; j < 4; ++j) acc[i][j] += av[i] * bv_[j];
    }
  }
#pragma unroll
  for (int j = 0; j < 4; ++j) {
    int dcol = c0 + tx * 4 + j;
    float bz = bo[dcol];
#pragma unroll
    for (int i = 0; i < 4; ++i) {
      int bt = bt0 + ty * 4 + i;
      out[(size_t)bt * DMODEL + dcol] = acc[i][j] + bz;
    }
  }
}

// ---------------------------------------------------------------------------
extern "C" void kernel_launch(void* const* d_in, const int* in_sizes, int n_in,
                              void* d_out, int out_size, void* d_ws, size_t ws_size,
                              hipStream_t stream) {
  const float* X   = (const float*)d_in[0];
  const float* Wq  = (const float*)d_in[1];
  const float* bq  = (const float*)d_in[2];
  const float* Wk  = (const float*)d_in[3];
  const float* bk  = (const float*)d_in[4];
  const float* Wv  = (const float*)d_in[5];
  const float* bv  = (const float*)d_in[6];
  const float* Wp  = (const float*)d_in[7];
  const float* Wo  = (const float*)d_in[8];
  const float* bo  = (const float*)d_in[9];
  const float* ub  = (const float*)d_in[10];
  const float* vbb = (const float*)d_in[11];

  float* ws = (float*)d_ws;
  float* qbuf = ws + Q_OFF;
  float* kbuf = ws + K_OFF;
  float* vbuf = ws + V_OFF;
  float* pbuf = ws + P_OFF;
  float* obuf = ws + O_OFF;
  float* pe   = ws + PE_OFF;

  float* out0 = (float*)d_out;
  float* attn = out0 + OUT0;

  pe_kernel<<<2047, 256, 0, stream>>>(pe);
  proj_qkv_kernel<<<dim3(128, 12), 256, 0, stream>>>(X, Wq, Wk, Wv, bq, bk, bv,
                                                     qbuf, kbuf, vbuf);
  pgemm_kernel<<<dim3(32, 4), 256, 0, stream>>>(pe, Wp, pbuf);
  attn_kernel<<<4096, 256, 0, stream>>>(qbuf, kbuf, vbuf, pbuf, ub, vbb, attn, obuf);
  oproj_kernel<<<dim3(128, 4), 256, 0, stream>>>(obuf, Wo, bo, out0);
}